// Round 6
// baseline (285.399 us; speedup 1.0000x reference)
//
#include <hip/hip_runtime.h>
#include <hip/hip_bf16.h>

// SDPA with materialized attention, two-pass streaming design.
// B=16, LQ=LK=2048, D=64. d_out = out [B,LQ,D] f32 then attn [B,LQ,LK] f32.
// K1: e = !mask * exp2(QK^T/8*log2e) -> attn region (f32, unnormalized),
//     per-row partial sums -> stashed in out[b][row][0..3].
// K2: rinv from partials; stream e: attn = e*rinv (in place) + PV via MFMA.
namespace {
constexpr int kB = 16;
constexpr int kLQ = 2048;
constexpr int kLK = 2048;
constexpr int kD = 64;
constexpr float kLog2e = 1.44269504088896340736f;
// K1 geometry: 64 q-rows x 512 k-cols per block, subchunks of 32 cols.
constexpr int kQT = 64;
constexpr int kKT = 512;
// LDS strides (bytes, padded vs bank conflicts)
constexpr int kKStrB = 144;   // K-stage row: 64 bf16 = 128B + 16 pad
constexpr int kMStrB = 40;    // mask-stage row: 32B + 8 pad
constexpr int kBStrB = 144;   // bounce row: 32 f32 = 128B + 16 pad
// K2 geometry: 16 q-rows, chunks of 256 cols.
constexpr int kChunk = 256;
constexpr int kEStrB = 528;   // e-chunk row: 256 bf16 = 512B + 16 pad
}

using short8 = __attribute__((ext_vector_type(8))) short;
using f32x4 = __attribute__((ext_vector_type(4))) float;

union S8U { short8 v; unsigned u[4]; };

static __device__ __forceinline__ unsigned pk2(float lo, float hi) {
    __hip_bfloat162 h = __float22bfloat162_rn(float2{lo, hi});
    unsigned short a = __builtin_bit_cast(unsigned short, h.x);
    unsigned short b = __builtin_bit_cast(unsigned short, h.y);
    return (unsigned)a | ((unsigned)b << 16);
}

// ---------------- K1: QK^T + mask + exp2 -> e (f32) + partial sums ----------------
__global__ __launch_bounds__(256, 4) void k1_qke(
    const float* __restrict__ qg, const float* __restrict__ kg,
    const void* __restrict__ maskg, float* __restrict__ attng,
    float* __restrict__ outg)
{
    __shared__ __align__(16) unsigned char s_kst[32 * kKStrB];     // K subchunk bf16 [32][64]
    __shared__ __align__(16) unsigned char s_mst[64 * kMStrB];     // mask flags [64][32]
    __shared__ __align__(16) unsigned char s_bnc[4][16 * kBStrB];  // e bounce [wave][16][32 f32]
    __shared__ int s_flag;

    const int tid = threadIdx.x;
    const int wave = tid >> 6;          // rowgroup 0..3
    const int lane = tid & 63;
    const int r16 = lane & 15;
    const int g = lane >> 4;

    const int blk = blockIdx.x;
    const int b = blk >> 7;             // 128 blocks per batch
    const int kt = (blk >> 5) & 3;      // k-tile 0..3 (512 cols each)
    const int qt = blk & 31;            // q-tile 0..31 (64 rows each)
    const int rows0 = qt * kQT;
    const int c0 = kt * kKT;

    // mask dtype detection: int32 0/1 words have bytes 1..3 == 0
    if (tid < 64) {
        unsigned w = ((const unsigned*)maskg)[tid];
        unsigned long long bal = __ballot((w & 0xFFFFFF00u) != 0u);
        if (tid == 0) s_flag = (bal != 0ull) ? 1 : 0;
    }
    __syncthreads();
    const bool mask_byte = (s_flag != 0);
    const unsigned char* mask_u8 = (const unsigned char*)maskg;
    const int* mask_i32 = (const int*)maskg;

    // Q fragment for this wave's 16 rows, scale folded (0.125 * log2e)
    short8 q0, q1;
    {
        const float4* qp = (const float4*)(qg + ((size_t)b * kLQ + rows0 + wave * 16 + r16) * kD);
        const float s = 0.125f * kLog2e;
        float4 x0 = qp[2*g + 0], x1 = qp[2*g + 1];
        float4 x2 = qp[2*g + 8], x3 = qp[2*g + 9];
        x0 *= s; x1 *= s; x2 *= s; x3 *= s;
        S8U a, c;
        a.u[0] = pk2(x0.x, x0.y); a.u[1] = pk2(x0.z, x0.w);
        a.u[2] = pk2(x1.x, x1.y); a.u[3] = pk2(x1.z, x1.w);
        c.u[0] = pk2(x2.x, x2.y); c.u[1] = pk2(x2.z, x2.w);
        c.u[2] = pk2(x3.x, x3.y); c.u[3] = pk2(x3.z, x3.w);
        q0 = a.v; q1 = c.v;
    }

    float wsum = 0.f;

    for (int sub = 0; sub < kKT / 32; ++sub) {
        const int csub = c0 + sub * 32;
        // ---- cooperative coalesced K stage: 32 rows x 64 d f32 -> bf16 LDS ----
        {
            const int krow = tid >> 3;
            const int d8 = (tid & 7) * 8;
            const float4* kp = (const float4*)(kg + ((size_t)b * kLK + csub + krow) * kD + d8);
            float4 y0 = kp[0], y1 = kp[1];
            S8U p;
            p.u[0] = pk2(y0.x, y0.y); p.u[1] = pk2(y0.z, y0.w);
            p.u[2] = pk2(y1.x, y1.y); p.u[3] = pk2(y1.z, y1.w);
            *(short8*)(s_kst + krow * kKStrB + d8 * 2) = p.v;
        }
        // ---- cooperative mask stage: 64 rows x 32 cols -> byte flags in LDS ----
        {
            const int mrow = tid >> 2;
            const int mc = (tid & 3) * 8;
            unsigned long long f;
            if (mask_byte) {
                f = *(const unsigned long long*)(mask_u8 +
                        ((size_t)b * kLQ + rows0 + mrow) * (size_t)kLK + csub + mc);
            } else {
                const int* mp = mask_i32 + ((size_t)b * kLQ + rows0 + mrow) * (size_t)kLK + csub + mc;
                const int4 m0 = *(const int4*)mp;
                const int4 m1 = *(const int4*)(mp + 4);
                f  = (m0.x ? 1ull : 0ull)       | (m0.y ? 1ull << 8 : 0ull)
                   | (m0.z ? 1ull << 16 : 0ull) | (m0.w ? 1ull << 24 : 0ull)
                   | (m1.x ? 1ull << 32 : 0ull) | (m1.y ? 1ull << 40 : 0ull)
                   | (m1.z ? 1ull << 48 : 0ull) | (m1.w ? 1ull << 56 : 0ull);
            }
            *(unsigned long long*)(s_mst + mrow * kMStrB + mc) = f;
        }
        __syncthreads();

        // ---- fragments from LDS, MFMA, mask, exp2 ----
        const short8 kA0 = *(const short8*)(s_kst + r16 * kKStrB + g * 16);
        const short8 kA1 = *(const short8*)(s_kst + r16 * kKStrB + 64 + g * 16);
        const short8 kB0 = *(const short8*)(s_kst + (16 + r16) * kKStrB + g * 16);
        const short8 kB1 = *(const short8*)(s_kst + (16 + r16) * kKStrB + 64 + g * 16);
        f32x4 accA = {0.f, 0.f, 0.f, 0.f}, accB = {0.f, 0.f, 0.f, 0.f};
        accA = __builtin_amdgcn_mfma_f32_16x16x32_bf16(kA0, q0, accA, 0, 0, 0);
        accA = __builtin_amdgcn_mfma_f32_16x16x32_bf16(kA1, q1, accA, 0, 0, 0);
        accB = __builtin_amdgcn_mfma_f32_16x16x32_bf16(kB0, q0, accB, 0, 0, 0);
        accB = __builtin_amdgcn_mfma_f32_16x16x32_bf16(kB1, q1, accB, 0, 0, 0);

        const unsigned mwA = *(const unsigned*)(s_mst + (wave * 16 + r16) * kMStrB + 4 * g);
        const unsigned mwB = *(const unsigned*)(s_mst + (wave * 16 + r16) * kMStrB + 16 + 4 * g);
        f32x4 eA, eB;
#pragma unroll
        for (int r = 0; r < 4; ++r) {
            eA[r] = ((mwA >> (8*r)) & 0xFFu) ? 0.f : __builtin_amdgcn_exp2f(accA[r]);
            eB[r] = ((mwB >> (8*r)) & 0xFFu) ? 0.f : __builtin_amdgcn_exp2f(accB[r]);
        }
        wsum += (eA[0] + eA[1]) + (eA[2] + eA[3]) + (eB[0] + eB[1]) + (eB[2] + eB[3]);
        // bounce e (f32) for coalesced global store
        *(f32x4*)(s_bnc[wave] + r16 * kBStrB + g * 16) = eA;
        *(f32x4*)(s_bnc[wave] + r16 * kBStrB + 64 + g * 16) = eB;
        __syncthreads();

        // ---- coalesced e store: 64 rows x 32 f32 ----
        {
            const int row = tid >> 2;
            const int cseg = tid & 3;
            const unsigned char* src = s_bnc[row >> 4] + (row & 15) * kBStrB + cseg * 32;
            const f32x4 v0 = *(const f32x4*)src;
            const f32x4 v1 = *(const f32x4*)(src + 16);
            float* dst = attng + ((size_t)b * kLQ + rows0 + row) * (size_t)kLK + csub + cseg * 8;
            *(f32x4*)dst = v0;
            *(f32x4*)(dst + 4) = v1;
        }
        // next iteration's stage writes are ordered by the loop-top barrier
    }
    // per-row partial sum for this k-tile -> stash in out[b][row][kt]
    wsum += __shfl_xor(wsum, 16, 64);
    wsum += __shfl_xor(wsum, 32, 64);
    if (g == 0)
        outg[((size_t)b * kLQ + rows0 + wave * 16 + r16) * kD + kt] = wsum;
}

// ---------------- K2: normalize attn in place + PV ----------------
__global__ __launch_bounds__(512, 2) void k2_norm_pv(
    const float* __restrict__ vg, float* __restrict__ attng,
    float* __restrict__ outg)
{
    __shared__ __align__(16) unsigned char s_e[16 * kEStrB];  // normalized e bf16 [16][256]
    __shared__ float s_red[16][kD];
    __shared__ float s_rinv[16];

    const int tid = threadIdx.x;
    const int wave = tid >> 6;
    const int lane = tid & 63;
    const int r16 = lane & 15;
    const int g = lane >> 4;

    const int blk = blockIdx.x;
    const int b = blk >> 7;
    const int row0 = (blk & 127) * 16;

    // row sums from the 4 stashed partials
    if (tid < 64) {
        const int r = tid >> 2, p = tid & 3;
        float ps = outg[((size_t)b * kLQ + row0 + r) * kD + p];
        ps += __shfl_xor(ps, 1, 64);
        ps += __shfl_xor(ps, 2, 64);
        if (p == 0) s_rinv[r] = __builtin_amdgcn_rcpf(ps);
    }
    __syncthreads();

    const int d0 = (wave & 3) * 16;
    const int kh = wave >> 2;           // k-half of each chunk
    f32x4 acc = {0.f, 0.f, 0.f, 0.f};
    const float* vbase = vg + (size_t)b * kLK * kD + d0 + r16;

    for (int chunk = 0; chunk < kLK / kChunk; ++chunk) {
        const int c0 = chunk * kChunk;
        // ---- stream e chunk: load f32, scale, store attn, pack bf16 to LDS ----
        {
            const int row = tid >> 5;
            const int cc = tid & 31;
            const float rinv = s_rinv[row];
            float* ap = attng + ((size_t)b * kLQ + row0 + row) * (size_t)kLK + c0 + cc * 8;
            f32x4 e0 = *(const f32x4*)ap;
            f32x4 e1 = *(const f32x4*)(ap + 4);
            e0 *= rinv; e1 *= rinv;
            *(f32x4*)ap = e0;
            *(f32x4*)(ap + 4) = e1;
            S8U p;
            p.u[0] = pk2(e0[0], e0[1]); p.u[1] = pk2(e0[2], e0[3]);
            p.u[2] = pk2(e1[0], e1[1]); p.u[3] = pk2(e1[2], e1[3]);
            *(short8*)(s_e + row * kEStrB + cc * 16) = p.v;
        }
        __syncthreads();
        // ---- PV over this chunk's kh-half (128 cols = 4 k-steps) ----
#pragma unroll
        for (int s = 0; s < 4; ++s) {
            const int kk = kh * 128 + s * 32 + 8 * g;       // chunk-local k base for this lane
            const short8 af = *(const short8*)(s_e + r16 * kEStrB + kk * 2);
            const float* vp = vbase + (size_t)(c0 + kk) * kD;
            float v0 = vp[0*kD], v1 = vp[1*kD], v2 = vp[2*kD], v3 = vp[3*kD];
            float v4 = vp[4*kD], v5 = vp[5*kD], v6 = vp[6*kD], v7 = vp[7*kD];
            S8U bv;
            bv.u[0] = pk2(v0, v1); bv.u[1] = pk2(v2, v3);
            bv.u[2] = pk2(v4, v5); bv.u[3] = pk2(v6, v7);
            acc = __builtin_amdgcn_mfma_f32_16x16x32_bf16(af, bv.v, acc, 0, 0, 0);
        }
        __syncthreads();   // PV reads done before next chunk overwrites s_e
    }

    // kh-split reduction and out store (overwrites the partial stash)
    if (kh == 1) {
#pragma unroll
        for (int r = 0; r < 4; ++r) s_red[4*g + r][d0 + r16] = acc[r];
    }
    __syncthreads();
    if (kh == 0) {
#pragma unroll
        for (int r = 0; r < 4; ++r) {
            const int m = 4*g + r;
            outg[((size_t)b * kLQ + row0 + m) * kD + d0 + r16] = acc[r] + s_red[m][d0 + r16];
        }
    }
}

extern "C" void kernel_launch(void* const* d_in, const int* in_sizes, int n_in,
                              void* d_out, int out_size, void* d_ws, size_t ws_size,
                              hipStream_t stream) {
    (void)in_sizes; (void)n_in; (void)out_size; (void)d_ws; (void)ws_size;
    const float* q = (const float*)d_in[0];
    const float* k = (const float*)d_in[1];
    const float* v = (const float*)d_in[2];
    const void* mask = d_in[3];
    float* out = (float*)d_out;
    float* attn = out + (size_t)kB * kLQ * kD;
    k1_qke<<<dim3(kB * 128), 256, 0, stream>>>(q, k, mask, attn, out);
    k2_norm_pv<<<dim3(kB * 128), 512, 0, stream>>>(v, attn, out);
}

// Round 7
// 284.225 us; speedup vs baseline: 1.0041x; 1.0041x over previous
//
#include <hip/hip_runtime.h>
#include <hip/hip_bf16.h>

// SDPA with materialized attention, two-pass streaming design, bf16 e via d_ws.
// B=16, LQ=LK=2048, D=64. d_out = out [B,LQ,D] f32 then attn [B,LQ,LK] f32.
// K1: e = !mask * exp2(QK^T/8*log2e) -> d_ws (bf16, unnormalized),
//     per-row partial sums -> stashed in out[b][row][0..3].
// K2: rinv from partials; stream e: attn = e*rinv (f32) + PV on unnormalized e,
//     out scaled by rinv at the end.
namespace {
constexpr int kB = 16;
constexpr int kLQ = 2048;
constexpr int kLK = 2048;
constexpr int kD = 64;
constexpr float kLog2e = 1.44269504088896340736f;
// K1 geometry: 64 q-rows x 512 k-cols per block, subchunks of 32 cols.
constexpr int kQT = 64;
constexpr int kKT = 512;
// LDS strides (bytes, padded vs bank conflicts)
constexpr int kKStrB = 144;   // K-stage row: 64 bf16 = 128B + 16 pad
constexpr int kMStrB = 40;    // mask-stage row: 32B + 8 pad
constexpr int kBStrB = 72;    // e-bounce row: 32 bf16 = 64B + 8 pad
// K2 geometry: 16 q-rows, chunks of 256 cols.
constexpr int kChunk = 256;
constexpr int kEStrB = 528;   // e-chunk row: 256 bf16 = 512B + 16 pad
}

using short8 = __attribute__((ext_vector_type(8))) short;
using f32x4 = __attribute__((ext_vector_type(4))) float;

union S8U { short8 v; unsigned u[4]; };

static __device__ __forceinline__ unsigned pk2(float lo, float hi) {
    __hip_bfloat162 h = __float22bfloat162_rn(float2{lo, hi});
    unsigned short a = __builtin_bit_cast(unsigned short, h.x);
    unsigned short b = __builtin_bit_cast(unsigned short, h.y);
    return (unsigned)a | ((unsigned)b << 16);
}
static __device__ __forceinline__ float bf2f(unsigned short s) {
    unsigned u = ((unsigned)s) << 16;
    return __builtin_bit_cast(float, u);
}

// ---------------- K1: QK^T + mask + exp2 -> e (bf16, ws) + partial sums ----------------
__global__ __launch_bounds__(256, 8) void k1_qke(
    const float* __restrict__ qg, const float* __restrict__ kg,
    const void* __restrict__ maskg, unsigned short* __restrict__ ews,
    float* __restrict__ outg)
{
    __shared__ __align__(16) unsigned char s_kst[32 * kKStrB];     // K subchunk bf16 [32][64]
    __shared__ __align__(16) unsigned char s_mst[64 * kMStrB];     // mask flags [64][32]
    __shared__ __align__(16) unsigned char s_bnc[4][16 * kBStrB];  // e bounce [wave][16][32 bf16]
    __shared__ int s_flag;

    const int tid = threadIdx.x;
    const int wave = tid >> 6;          // rowgroup 0..3
    const int lane = tid & 63;
    const int r16 = lane & 15;
    const int g = lane >> 4;

    const int blk = blockIdx.x;
    const int b = blk >> 7;             // 128 blocks per batch
    const int kt = (blk >> 5) & 3;      // k-tile 0..3 (512 cols each)
    const int qt = blk & 31;            // q-tile 0..31 (64 rows each)
    const int rows0 = qt * kQT;
    const int c0 = kt * kKT;

    // mask dtype detection: int32 0/1 words have bytes 1..3 == 0
    if (tid < 64) {
        unsigned w = ((const unsigned*)maskg)[tid];
        unsigned long long bal = __ballot((w & 0xFFFFFF00u) != 0u);
        if (tid == 0) s_flag = (bal != 0ull) ? 1 : 0;
    }
    __syncthreads();
    const bool mask_byte = (s_flag != 0);
    const unsigned char* mask_u8 = (const unsigned char*)maskg;
    const int* mask_i32 = (const int*)maskg;

    // Q fragment for this wave's 16 rows, scale folded (0.125 * log2e)
    short8 q0, q1;
    {
        const float4* qp = (const float4*)(qg + ((size_t)b * kLQ + rows0 + wave * 16 + r16) * kD);
        const float s = 0.125f * kLog2e;
        float4 x0 = qp[2*g + 0], x1 = qp[2*g + 1];
        float4 x2 = qp[2*g + 8], x3 = qp[2*g + 9];
        x0 *= s; x1 *= s; x2 *= s; x3 *= s;
        S8U a, c;
        a.u[0] = pk2(x0.x, x0.y); a.u[1] = pk2(x0.z, x0.w);
        a.u[2] = pk2(x1.x, x1.y); a.u[3] = pk2(x1.z, x1.w);
        c.u[0] = pk2(x2.x, x2.y); c.u[1] = pk2(x2.z, x2.w);
        c.u[2] = pk2(x3.x, x3.y); c.u[3] = pk2(x3.z, x3.w);
        q0 = a.v; q1 = c.v;
    }

    float wsum = 0.f;

    for (int sub = 0; sub < kKT / 32; ++sub) {
        const int csub = c0 + sub * 32;
        // ---- cooperative coalesced K stage: 32 rows x 64 d f32 -> bf16 LDS ----
        {
            const int krow = tid >> 3;
            const int d8 = (tid & 7) * 8;
            const float4* kp = (const float4*)(kg + ((size_t)b * kLK + csub + krow) * kD + d8);
            float4 y0 = kp[0], y1 = kp[1];
            S8U p;
            p.u[0] = pk2(y0.x, y0.y); p.u[1] = pk2(y0.z, y0.w);
            p.u[2] = pk2(y1.x, y1.y); p.u[3] = pk2(y1.z, y1.w);
            *(short8*)(s_kst + krow * kKStrB + d8 * 2) = p.v;
        }
        // ---- cooperative mask stage: 64 rows x 32 cols -> byte flags in LDS ----
        {
            const int mrow = tid >> 2;
            const int mc = (tid & 3) * 8;
            unsigned long long f;
            if (mask_byte) {
                f = *(const unsigned long long*)(mask_u8 +
                        ((size_t)b * kLQ + rows0 + mrow) * (size_t)kLK + csub + mc);
            } else {
                const int* mp = mask_i32 + ((size_t)b * kLQ + rows0 + mrow) * (size_t)kLK + csub + mc;
                const int4 m0 = *(const int4*)mp;
                const int4 m1 = *(const int4*)(mp + 4);
                f  = (m0.x ? 1ull : 0ull)       | (m0.y ? 1ull << 8 : 0ull)
                   | (m0.z ? 1ull << 16 : 0ull) | (m0.w ? 1ull << 24 : 0ull)
                   | (m1.x ? 1ull << 32 : 0ull) | (m1.y ? 1ull << 40 : 0ull)
                   | (m1.z ? 1ull << 48 : 0ull) | (m1.w ? 1ull << 56 : 0ull);
            }
            *(unsigned long long*)(s_mst + mrow * kMStrB + mc) = f;
        }
        __syncthreads();

        // ---- fragments from LDS, MFMA, mask, exp2 ----
        const short8 kA0 = *(const short8*)(s_kst + r16 * kKStrB + g * 16);
        const short8 kA1 = *(const short8*)(s_kst + r16 * kKStrB + 64 + g * 16);
        const short8 kB0 = *(const short8*)(s_kst + (16 + r16) * kKStrB + g * 16);
        const short8 kB1 = *(const short8*)(s_kst + (16 + r16) * kKStrB + 64 + g * 16);
        f32x4 accA = {0.f, 0.f, 0.f, 0.f}, accB = {0.f, 0.f, 0.f, 0.f};
        accA = __builtin_amdgcn_mfma_f32_16x16x32_bf16(kA0, q0, accA, 0, 0, 0);
        accA = __builtin_amdgcn_mfma_f32_16x16x32_bf16(kA1, q1, accA, 0, 0, 0);
        accB = __builtin_amdgcn_mfma_f32_16x16x32_bf16(kB0, q0, accB, 0, 0, 0);
        accB = __builtin_amdgcn_mfma_f32_16x16x32_bf16(kB1, q1, accB, 0, 0, 0);

        const unsigned mwA = *(const unsigned*)(s_mst + (wave * 16 + r16) * kMStrB + 4 * g);
        const unsigned mwB = *(const unsigned*)(s_mst + (wave * 16 + r16) * kMStrB + 16 + 4 * g);
        float eA[4], eB[4];
#pragma unroll
        for (int r = 0; r < 4; ++r) {
            eA[r] = ((mwA >> (8*r)) & 0xFFu) ? 0.f : __builtin_amdgcn_exp2f(accA[r]);
            eB[r] = ((mwB >> (8*r)) & 0xFFu) ? 0.f : __builtin_amdgcn_exp2f(accB[r]);
        }
        wsum += (eA[0] + eA[1]) + (eA[2] + eA[3]) + (eB[0] + eB[1]) + (eB[2] + eB[3]);
        // bounce e (bf16) for coalesced global store
        uint2 pA{ pk2(eA[0], eA[1]), pk2(eA[2], eA[3]) };
        uint2 pB{ pk2(eB[0], eB[1]), pk2(eB[2], eB[3]) };
        *(uint2*)(s_bnc[wave] + r16 * kBStrB + 8 * g) = pA;
        *(uint2*)(s_bnc[wave] + r16 * kBStrB + 32 + 8 * g) = pB;
        __syncthreads();

        // ---- coalesced e store: 64 rows x 32 bf16 (64 B/row) ----
        {
            const int row = tid >> 2;
            const int seg = tid & 3;
            const S8U* src = (const S8U*)(s_bnc[row >> 4] + (row & 15) * kBStrB + seg * 16);
            unsigned short* dst = ews + ((size_t)b * kLQ + rows0 + row) * (size_t)kLK + csub + seg * 8;
            *(short8*)dst = src->v;
        }
    }
    // per-row partial sum for this k-tile -> stash in out[b][row][kt]
    wsum += __shfl_xor(wsum, 16, 64);
    wsum += __shfl_xor(wsum, 32, 64);
    if (g == 0)
        outg[((size_t)b * kLQ + rows0 + wave * 16 + r16) * kD + kt] = wsum;
}

// ---------------- K2: attn = e*rinv (f32) + PV on unnormalized e ----------------
__global__ __launch_bounds__(512, 8) void k2_norm_pv(
    const float* __restrict__ vg, const unsigned short* __restrict__ ews,
    float* __restrict__ attng, float* __restrict__ outg)
{
    __shared__ __align__(16) unsigned char s_e[16 * kEStrB];  // raw e bf16 [16][256]
    __shared__ float s_red[16][kD];
    __shared__ float s_rinv[16];

    const int tid = threadIdx.x;
    const int wave = tid >> 6;
    const int lane = tid & 63;
    const int r16 = lane & 15;
    const int g = lane >> 4;

    const int blk = blockIdx.x;
    const int b = blk >> 7;
    const int row0 = (blk & 127) * 16;

    // row sums from the 4 stashed partials
    if (tid < 64) {
        const int r = tid >> 2, p = tid & 3;
        float ps = outg[((size_t)b * kLQ + row0 + r) * kD + p];
        ps += __shfl_xor(ps, 1, 64);
        ps += __shfl_xor(ps, 2, 64);
        if (p == 0) s_rinv[r] = __builtin_amdgcn_rcpf(ps);
    }
    __syncthreads();

    const int d0 = (wave & 3) * 16;
    const int kh = wave >> 2;           // k-half of each chunk
    f32x4 acc = {0.f, 0.f, 0.f, 0.f};
    const float* vbase = vg + (size_t)b * kLK * kD + d0 + r16;

    for (int chunk = 0; chunk < kLK / kChunk; ++chunk) {
        const int c0 = chunk * kChunk;
        // ---- stream e chunk (bf16): raw copy to LDS + normalized f32 attn store ----
        {
            const int row = tid >> 5;
            const int cc = tid & 31;
            const float rinv = s_rinv[row];
            const unsigned short* ep = ews + ((size_t)b * kLQ + row0 + row) * (size_t)kLK + c0 + cc * 8;
            const short8 ev = *(const short8*)ep;
            *(short8*)(s_e + row * kEStrB + cc * 16) = ev;     // raw (unnormalized)
            float* ap = attng + ((size_t)b * kLQ + row0 + row) * (size_t)kLK + c0 + cc * 8;
            f32x4 a0, a1;
            a0[0] = bf2f((unsigned short)ev[0]) * rinv;
            a0[1] = bf2f((unsigned short)ev[1]) * rinv;
            a0[2] = bf2f((unsigned short)ev[2]) * rinv;
            a0[3] = bf2f((unsigned short)ev[3]) * rinv;
            a1[0] = bf2f((unsigned short)ev[4]) * rinv;
            a1[1] = bf2f((unsigned short)ev[5]) * rinv;
            a1[2] = bf2f((unsigned short)ev[6]) * rinv;
            a1[3] = bf2f((unsigned short)ev[7]) * rinv;
            *(f32x4*)ap = a0;
            *(f32x4*)(ap + 4) = a1;
        }
        __syncthreads();
        // ---- PV over this chunk's kh-half (128 cols = 4 k-steps), unnormalized ----
#pragma unroll
        for (int s = 0; s < 4; ++s) {
            const int kk = kh * 128 + s * 32 + 8 * g;       // chunk-local k base for this lane
            const short8 af = *(const short8*)(s_e + r16 * kEStrB + kk * 2);
            const float* vp = vbase + (size_t)(c0 + kk) * kD;
            float v0 = vp[0*kD], v1 = vp[1*kD], v2 = vp[2*kD], v3 = vp[3*kD];
            float v4 = vp[4*kD], v5 = vp[5*kD], v6 = vp[6*kD], v7 = vp[7*kD];
            S8U bv;
            bv.u[0] = pk2(v0, v1); bv.u[1] = pk2(v2, v3);
            bv.u[2] = pk2(v4, v5); bv.u[3] = pk2(v6, v7);
            acc = __builtin_amdgcn_mfma_f32_16x16x32_bf16(af, bv.v, acc, 0, 0, 0);
        }
        __syncthreads();   // PV reads done before next chunk overwrites s_e
    }

    // kh-split reduction and out store (overwrites the partial stash), scaled by rinv
    if (kh == 1) {
#pragma unroll
        for (int r = 0; r < 4; ++r) s_red[4*g + r][d0 + r16] = acc[r];
    }
    __syncthreads();
    if (kh == 0) {
#pragma unroll
        for (int r = 0; r < 4; ++r) {
            const int m = 4*g + r;
            outg[((size_t)b * kLQ + row0 + m) * kD + d0 + r16] =
                (acc[r] + s_red[m][d0 + r16]) * s_rinv[m];
        }
    }
}

extern "C" void kernel_launch(void* const* d_in, const int* in_sizes, int n_in,
                              void* d_out, int out_size, void* d_ws, size_t ws_size,
                              hipStream_t stream) {
    (void)in_sizes; (void)n_in; (void)out_size; (void)ws_size;
    const float* q = (const float*)d_in[0];
    const float* k = (const float*)d_in[1];
    const float* v = (const float*)d_in[2];
    const void* mask = d_in[3];
    float* out = (float*)d_out;
    float* attn = out + (size_t)kB * kLQ * kD;
    unsigned short* ews = (unsigned short*)d_ws;   // 134 MB bf16 e (ws ~1 GB)
    k1_qke<<<dim3(kB * 128), 256, 0, stream>>>(q, k, mask, ews, out);
    k2_norm_pv<<<dim3(kB * 128), 512, 0, stream>>>(v, ews, attn, out);
}